// Round 6
// baseline (175.752 us; speedup 1.0000x reference)
//
#include <hip/hip_runtime.h>

// DiscriminatorIndependent: 1024 tiny MLPs (2->4->1, relu), B=16384.
//
// R1-R5: payload must use async global->LDS (gload_lds w=16); register-dest
//   loads get latency-serialized by the compiler.
// R6-R9 postmortem: the ONLY invariant between the two 41.5us kernels (R0,R6)
//   is per-CU DS-pipe work: ~86Kcy (shfl=ds_bpermute ~12cy x 96/48 per thread
//   + scalar ds_read_b32 payload reads) ~= 36us ~= the measured time. Traffic
//   (R7), occupancy (R6), and vmcnt pipelining (R9) all moved counters but
//   not time. The shuffle-heavy reduction IS the kernel.
//
// R10: keep R6's oversubscribed one-shot staging; cut DS 3.5x; zero barriers.
//   - K=4 MLPs per LANE: payload read = 1 ds_read_b128 per row per array
//     (4/thread vs 16 scalar), conflict-free (16B stride).
//   - A wave's 64 lanes span the full 256-MLP quarter -> row reduction is 6
//     shfl in ONE wave; lane0 atomicAdds directly. No red[], no 2nd barrier.
//     12 shfl/thread vs 48.
//   - Each wave stages exactly the 2 rows it computes -> its own vmcnt(0)
//     suffices; NO __syncthreads anywhere. 4 waves/block fully decoupled.
//   DS/CU: 86K -> ~25Kcy. Params 17 float4/thread (4-way redundant across
//   waves, L1-served; L2 bytes unchanged at 17KB/block).

constexpr int N_MLP = 1024;
constexpr int BATCH = 16384;
constexpr int ROWS = 8;            // batch rows per block (2 per wave)
constexpr int NTHREADS = 256;      // 4 waves
constexpr int QN = 256;            // MLPs per block (quarter of N)
constexpr int NQ = N_MLP / QN;     // 4 quarters
constexpr int NBLK = (BATCH / ROWS) * NQ;   // 8192

typedef __attribute__((address_space(3))) void lds_void;
typedef const __attribute__((address_space(1))) void gbl_void;

__global__ __launch_bounds__(256)
void zero_out_kernel(float* __restrict__ out) {
    out[blockIdx.x * 256 + threadIdx.x] = 0.0f;
}

__global__ __launch_bounds__(NTHREADS, 4)
void disc_mlp_kernel(const float* __restrict__ x,
                     const float* __restrict__ xa,
                     const float* __restrict__ W1,
                     const float* __restrict__ b1,
                     const float* __restrict__ W2,
                     const float* __restrict__ b2,
                     float* __restrict__ out)
{
    __shared__ float xbuf[ROWS * QN];   // 8 KB
    __shared__ float abuf[ROWS * QN];   // 8 KB

    const int t    = threadIdx.x;
    const int lane = t & 63;
    const int wave = t >> 6;
    const int q    = blockIdx.x & (NQ - 1);   // n-quarter
    const int rb   = blockIdx.x >> 2;         // row tile
    const int b0   = rb * ROWS;
    const int n0   = q * QN + lane * 4;       // first of this LANE's 4 MLPs

    // ---- async staging: wave w stages rows 2w, 2w+1 (the rows IT computes) ----
    const float* gx = x  + q * QN;
    const float* ga = xa + q * QN;
#pragma unroll
    for (int i = 0; i < 2; ++i) {
        const int r = wave * 2 + i;
        const size_t off = (size_t)(b0 + r) * N_MLP + lane * 4;
        __builtin_amdgcn_global_load_lds((gbl_void*)(gx + off),
            (lds_void*)&xbuf[r * QN + lane * 4], 16, 0, 0);
        __builtin_amdgcn_global_load_lds((gbl_void*)(ga + off),
            (lds_void*)&abuf[r * QN + lane * 4], 16, 0, 0);
    }

    // ---- params for 4 consecutive MLPs (issued after staging; same vmcnt) ----
    // W1[m] = 8 floats [h][e]: wa=(h0e0,h0e1,h1e0,h1e1), wb=(h2e0,h2e1,h3e0,h3e1)
    float4 wa[4], wb[4], bv[4], wv[4];
#pragma unroll
    for (int m = 0; m < 4; ++m) {
        wa[m] = reinterpret_cast<const float4*>(W1)[(size_t)(n0 + m) * 2];
        wb[m] = reinterpret_cast<const float4*>(W1)[(size_t)(n0 + m) * 2 + 1];
        bv[m] = reinterpret_cast<const float4*>(b1)[n0 + m];
        wv[m] = reinterpret_cast<const float4*>(W2)[n0 + m];
    }
    const float4 b2v = reinterpret_cast<const float4*>(b2)[n0 >> 2];
    const float bsum = (b2v.x + b2v.y) + (b2v.z + b2v.w);

    // per-wave drain: this wave's staged rows (and its params) are resident.
    asm volatile("s_waitcnt vmcnt(0)" ::: "memory");

    // ---- compute + reduce: 2 rows, all within this wave ----
#pragma unroll
    for (int i = 0; i < 2; ++i) {
        const int r = wave * 2 + i;
        const float4 xv = reinterpret_cast<const float4*>(xbuf)[r * (QN / 4) + lane];
        const float4 av = reinterpret_cast<const float4*>(abuf)[r * (QN / 4) + lane];
        const float xe[4] = {xv.x, xv.y, xv.z, xv.w};
        const float ae[4] = {av.x, av.y, av.z, av.w};
        float s = bsum;
#pragma unroll
        for (int m = 0; m < 4; ++m) {
            float h0 = fmaf(wa[m].x, xe[m], fmaf(wa[m].y, ae[m], bv[m].x));
            float h1 = fmaf(wa[m].z, xe[m], fmaf(wa[m].w, ae[m], bv[m].y));
            float h2 = fmaf(wb[m].x, xe[m], fmaf(wb[m].y, ae[m], bv[m].z));
            float h3 = fmaf(wb[m].z, xe[m], fmaf(wb[m].w, ae[m], bv[m].w));
            s = fmaf(wv[m].x, fmaxf(h0, 0.0f), s);
            s = fmaf(wv[m].y, fmaxf(h1, 0.0f), s);
            s = fmaf(wv[m].z, fmaxf(h2, 0.0f), s);
            s = fmaf(wv[m].w, fmaxf(h3, 0.0f), s);
        }
        // row-sum across this wave's 64 lanes (= all 256 MLPs of the quarter)
        s += __shfl_down(s, 32);
        s += __shfl_down(s, 16);
        s += __shfl_down(s, 8);
        s += __shfl_down(s, 4);
        s += __shfl_down(s, 2);
        s += __shfl_down(s, 1);
        if (lane == 0)
            atomicAdd(out + b0 + r, s * (1.0f / (float)N_MLP));
    }
}

extern "C" void kernel_launch(void* const* d_in, const int* in_sizes, int n_in,
                              void* d_out, int out_size, void* d_ws, size_t ws_size,
                              hipStream_t stream) {
    const float* x  = (const float*)d_in[0];
    const float* xa = (const float*)d_in[1];
    const float* W1 = (const float*)d_in[2];
    const float* b1 = (const float*)d_in[3];
    const float* W2 = (const float*)d_in[4];
    const float* b2 = (const float*)d_in[5];
    float* out = (float*)d_out;

    zero_out_kernel<<<BATCH / 256, 256, 0, stream>>>(out);
    disc_mlp_kernel<<<NBLK, NTHREADS, 0, stream>>>(x, xa, W1, b1, W2, b2, out);
}

// Round 7
// 148.669 us; speedup vs baseline: 1.1822x; 1.1822x over previous
//
#include <hip/hip_runtime.h>

// DiscriminatorIndependent: 1024 tiny MLPs (2->4->1, relu), B=16384.
//
// Ledger: R0(41.9)/R6(41.5) are the floor; R5/R7/R8/R9/R10 all regressed,
// each with an identified self-inflicted poison (compiler-serialized reg
// loads / atomics-in-drain / serial double-drain / persistent lockstep /
// stride-128B param gather = 58us of L1 transactions). Surviving theory:
// time ~= payload delivery (~20us: 128MB at ~6.3TB/s) + DS-pipe time
// (~20us: R0 and R6 both ~20K DS wave-instrs/CU, shfl=ds_bpermute
// dominated) -- the phases sum inside each wave.
//
// R11: R6 VERBATIM except the reduction moves off the DS pipe: the 6-step
// __shfl_down tree (6 ds_bpermute) becomes the classic GCN DPP cross-lane
// sum (row_shr:1/2/4/8 + row_bcast:15/31 via update_dpp, old=0) = 12 VALU
// ops, ZERO DS. Result lands in lane 63. DS wave-instrs/block: 265 -> ~73.
// Clean single-variable A/B on the DS theory: no mapping change, no new
// gathers, no new barriers.

constexpr int N_MLP = 1024;
constexpr int BATCH = 16384;
constexpr int ROWS = 8;        // batch rows per block
constexpr int NTHREADS = 256;  // 4 waves; covers QN MLPs
constexpr int QN = 256;        // MLPs per block (quarter of N)
constexpr int NQ = N_MLP / QN; // 4 quarters

typedef __attribute__((address_space(3))) void lds_void;
typedef const __attribute__((address_space(1))) void gbl_void;

// v += value from DPP-permuted v (invalid source lanes contribute old=0).
template<int CTRL, int ROW_MASK>
__device__ __forceinline__ float dpp_add(float v) {
    int s = __builtin_amdgcn_update_dpp(0, __float_as_int(v),
                                        CTRL, ROW_MASK, 0xf, false);
    return v + __int_as_float(s);
}

// Full wave64 sum on the VALU pipe; total ends in lane 63.
__device__ __forceinline__ float wave_sum_dpp(float v) {
    v = dpp_add<0x111, 0xf>(v);   // row_shr:1
    v = dpp_add<0x112, 0xf>(v);   // row_shr:2
    v = dpp_add<0x114, 0xf>(v);   // row_shr:4
    v = dpp_add<0x118, 0xf>(v);   // row_shr:8  -> lane15 of each row = row sum
    v = dpp_add<0x142, 0xa>(v);   // row_bcast:15 -> rows 1,3: lane31=sum(0..31), lane63=sum(32..63)
    v = dpp_add<0x143, 0xc>(v);   // row_bcast:31 -> rows 2,3: lane63=sum(0..63)
    return v;
}

__global__ __launch_bounds__(256)
void zero_out_kernel(float* __restrict__ out) {
    out[blockIdx.x * 256 + threadIdx.x] = 0.0f;
}

__global__ __launch_bounds__(NTHREADS, 8)
void disc_mlp_kernel(const float* __restrict__ x,
                     const float* __restrict__ xa,
                     const float* __restrict__ W1,
                     const float* __restrict__ b1,
                     const float* __restrict__ W2,
                     const float* __restrict__ b2,
                     float* __restrict__ out)
{
    __shared__ float xbuf[ROWS * QN];   // 8 KB
    __shared__ float abuf[ROWS * QN];   // 8 KB
    __shared__ float red[NTHREADS / 64][ROWS];

    const int t    = threadIdx.x;
    const int lane = t & 63;
    const int wave = t >> 6;
    const int q  = blockIdx.x & (NQ - 1);  // n-quarter
    const int rb = blockIdx.x >> 2;        // row tile
    const int b0 = rb * ROWS;
    const int n  = q * QN + t;             // this thread's MLP

    // ---- this MLP's params -> 17 registers (L2-resident, overlaps staging) ----
    const float4 p0 = reinterpret_cast<const float4*>(W1)[(size_t)n * 2];
    const float4 p1 = reinterpret_cast<const float4*>(W1)[(size_t)n * 2 + 1];
    const float4 bb = reinterpret_cast<const float4*>(b1)[n];
    const float4 ww = reinterpret_cast<const float4*>(W2)[n];
    const float  b2r = b2[n];

    // ---- async global->LDS staging: each wave stages 2 rows of x and xa ----
    // Per (wave,row): 64 lanes x 16B = 1KB = one 256-float quarter-row.
    const float* gx = x  + (size_t)b0 * N_MLP + q * QN;
    const float* ga = xa + (size_t)b0 * N_MLP + q * QN;
#pragma unroll
    for (int i = 0; i < ROWS / 4; ++i) {
        const int r = wave * (ROWS / 4) + i;
        const float* srcx = gx + (size_t)r * N_MLP + lane * 4;
        const float* srca = ga + (size_t)r * N_MLP + lane * 4;
        __builtin_amdgcn_global_load_lds((gbl_void*)srcx,
                                         (lds_void*)&xbuf[r * QN + lane * 4],
                                         16, 0, 0);
        __builtin_amdgcn_global_load_lds((gbl_void*)srca,
                                         (lds_void*)&abuf[r * QN + lane * 4],
                                         16, 0, 0);
    }
    __syncthreads();   // drains vmcnt: all 16 KB resident

    const float A[4]   = {p0.x, p0.z, p1.x, p1.z};
    const float C[4]   = {p0.y, p0.w, p1.y, p1.w};
    const float B1r[4] = {bb.x, bb.y, bb.z, bb.w};
    const float V[4]   = {ww.x, ww.y, ww.z, ww.w};

    // ---- compute from LDS ----
    float acc[ROWS];
#pragma unroll
    for (int r = 0; r < ROWS; ++r) {
        const float xe  = xbuf[r * QN + t];
        const float xae = abuf[r * QN + t];
        float s = b2r;
#pragma unroll
        for (int j = 0; j < 4; ++j) {
            float h = fmaf(A[j], xe, fmaf(C[j], xae, B1r[j]));
            h = fmaxf(h, 0.0f);
            s = fmaf(V[j], h, s);
        }
        acc[r] = s;
    }

    // ---- reduce each row across 64 lanes on the VALU pipe (DPP, no DS) ----
#pragma unroll
    for (int r = 0; r < ROWS; ++r) {
        const float v = wave_sum_dpp(acc[r]);
        if (lane == 63) red[wave][r] = v;   // lane 63 holds the wave total
    }
    __syncthreads();
    if (t < ROWS) {
        float s = (red[0][t] + red[1][t]) + (red[2][t] + red[3][t]);
        atomicAdd(out + b0 + t, s * (1.0f / (float)N_MLP));
    }
}

extern "C" void kernel_launch(void* const* d_in, const int* in_sizes, int n_in,
                              void* d_out, int out_size, void* d_ws, size_t ws_size,
                              hipStream_t stream) {
    const float* x  = (const float*)d_in[0];
    const float* xa = (const float*)d_in[1];
    const float* W1 = (const float*)d_in[2];
    const float* b1 = (const float*)d_in[3];
    const float* W2 = (const float*)d_in[4];
    const float* b2 = (const float*)d_in[5];
    float* out = (float*)d_out;

    zero_out_kernel<<<BATCH / 256, 256, 0, stream>>>(out);
    disc_mlp_kernel<<<(BATCH / ROWS) * NQ, NTHREADS, 0, stream>>>(x, xa, W1, b1, W2, b2, out);
}